// Round 1
// baseline (328.926 us; speedup 1.0000x reference)
//
#include <hip/hip_runtime.h>
#include <hip/hip_bf16.h>
#include <stdint.h>

// Problem constants
#define BATCH 2
#define S_LEN 2048
#define EMB   1024
#define NHEAD 16
#define HDIM  64
// M for all GEMMs = BATCH*S_LEN = 4096, N = K = EMB = 1024

typedef __attribute__((ext_vector_type(8))) __bf16 bf16x8;
typedef __attribute__((ext_vector_type(4))) __bf16 bf16x4;
typedef __attribute__((ext_vector_type(4))) float  f32x4;

__device__ __forceinline__ void gload_lds16(const void* g, void* l) {
    // width-16 global->LDS DMA; LDS dest is wave-uniform base + lane*16
    __builtin_amdgcn_global_load_lds(
        (__attribute__((address_space(1))) void*)g,
        (__attribute__((address_space(3))) void*)l,
        16, 0, 0);
}

// ---------------------------------------------------------------------------
// fp32 -> bf16 conversion (vectorized, 4 elems/thread)
// ---------------------------------------------------------------------------
__global__ void f2b_kernel(const float* __restrict__ s, __bf16* __restrict__ d, int n4) {
    int i = blockIdx.x * blockDim.x + threadIdx.x;
    if (i >= n4) return;
    float4 v = reinterpret_cast<const float4*>(s)[i];
    bf16x4 o = { (__bf16)v.x, (__bf16)v.y, (__bf16)v.z, (__bf16)v.w };
    reinterpret_cast<bf16x4*>(d)[i] = o;
}

// ---------------------------------------------------------------------------
// NT GEMM: C[M,N] = A[M,K] * W[N,K]^T + bias[N]
// OUT_MODE 0: fp32 row-major [M,N]
// OUT_MODE 1: bf16 into [B, H, S, HD]  (row -> (b,s), col -> (h,d))
// 128x128 tile, 4 waves, 4x4 acc of 16x16x32 bf16 MFMA, BK=32.
// ---------------------------------------------------------------------------
template <int OUT_MODE>
__global__ __launch_bounds__(256)
void gemm_nt(const __bf16* __restrict__ A, const __bf16* __restrict__ W,
             const float* __restrict__ bias, void* __restrict__ out,
             int M, int N, int K) {
    __shared__ __align__(16) __bf16 As[128 * 32];
    __shared__ __align__(16) __bf16 Bs[128 * 32];

    const int t    = threadIdx.x;
    const int w    = t >> 6;
    const int lane = t & 63;
    const int m0   = blockIdx.y * 128;
    const int n0   = blockIdx.x * 128;
    const int wr   = (w >> 1) * 64;   // wave row offset in tile
    const int wc   = (w & 1) * 64;    // wave col offset in tile
    const int fr   = lane & 15;       // fragment row (A) / col (B)
    const int kg   = (lane >> 4) * 8; // fragment k offset

    f32x4 acc[4][4];
#pragma unroll
    for (int i = 0; i < 4; ++i)
#pragma unroll
        for (int j = 0; j < 4; ++j) acc[i][j] = (f32x4){0.f, 0.f, 0.f, 0.f};

    for (int kt = 0; kt < K; kt += 32) {
        // stage A,B tiles: 128x32 bf16 = 8KB each; 256 thr * 16B = 4KB/instr
#pragma unroll
        for (int i = 0; i < 2; ++i) {
            int chunk = i * 256 + t;      // 16B-chunk index in tile
            int row   = chunk >> 2;
            int col   = (chunk & 3) * 8;
            gload_lds16(A + (size_t)(m0 + row) * K + kt + col,
                        (char*)As + i * 4096 + w * 1024);
            gload_lds16(W + (size_t)(n0 + row) * K + kt + col,
                        (char*)Bs + i * 4096 + w * 1024);
        }
        __syncthreads();

        bf16x8 af[4], bfv[4];
#pragma unroll
        for (int m = 0; m < 4; ++m)
            af[m] = *(const bf16x8*)&As[(wr + m * 16 + fr) * 32 + kg];
#pragma unroll
        for (int n = 0; n < 4; ++n)
            bfv[n] = *(const bf16x8*)&Bs[(wc + n * 16 + fr) * 32 + kg];
#pragma unroll
        for (int m = 0; m < 4; ++m)
#pragma unroll
            for (int n = 0; n < 4; ++n)
                acc[m][n] = __builtin_amdgcn_mfma_f32_16x16x32_bf16(
                    af[m], bfv[n], acc[m][n], 0, 0, 0);
        __syncthreads();
    }

    // epilogue: C/D layout col = lane&15, row = (lane>>4)*4 + j
    const int rbase = (lane >> 4) * 4;
#pragma unroll
    for (int m = 0; m < 4; ++m) {
#pragma unroll
        for (int n = 0; n < 4; ++n) {
            int col  = n0 + wc + n * 16 + fr;
            float bv = bias[col];
#pragma unroll
            for (int j = 0; j < 4; ++j) {
                int row = m0 + wr + m * 16 + rbase + j;
                float v = acc[m][n][j] + bv;
                if (OUT_MODE == 0) {
                    ((float*)out)[(size_t)row * N + col] = v;
                } else {
                    int b = row >> 11, s = row & (S_LEN - 1);
                    int h = col >> 6,  d = col & (HDIM - 1);
                    ((__bf16*)out)[(((size_t)(b * NHEAD + h)) * S_LEN + s) * HDIM + d] =
                        (__bf16)v;
                }
            }
        }
    }
}

// ---------------------------------------------------------------------------
// Block-causal flash attention.
// Q,K,V: [B,H,S,HD] bf16.  out: [B,S,E] bf16 (head h -> cols h*64..h*64+63).
// Block: 256 thr = 4 waves; q-tile = 64 rows (wave w owns rows +w*16).
// KV tile = 32 = BLK -> no element masking; waves 0,1 skip the last (odd)
// kv tile, waves 2,3 process it. Online softmax, stats per-lane per-reg.
// ---------------------------------------------------------------------------
__global__ __launch_bounds__(256)
void attn_kernel(const __bf16* __restrict__ Q, const __bf16* __restrict__ Kv,
                 const __bf16* __restrict__ V, __bf16* __restrict__ out) {
    __shared__ __align__(16) __bf16 Kt[32][72];      // K tile, padded (+8)
    __shared__ __align__(16) __bf16 VtT[64][40];     // V tile transposed [d][key]
    __shared__ __align__(16) __bf16 Pl[4][16][40];   // per-wave P, padded

    const int t    = threadIdx.x;
    const int w    = t >> 6;
    const int lane = t & 63;
    const int qt   = blockIdx.x;  // 0..31 (q-tiles of 64)
    const int bh   = blockIdx.y;  // 0..31 (b*H+h)

    const __bf16* Qb = Q  + (size_t)bh * S_LEN * HDIM;
    const __bf16* Kb = Kv + (size_t)bh * S_LEN * HDIM;
    const __bf16* Vb = V  + (size_t)bh * S_LEN * HDIM;

    const int fr  = lane & 15;
    const int kg  = (lane >> 4) * 8;
    const int qr0 = qt * 64 + w * 16;

    // Q fragments in registers: A-layout, rows = q, k = d (2 k-steps of 32)
    bf16x8 qa[2];
#pragma unroll
    for (int s = 0; s < 2; ++s)
        qa[s] = *(const bf16x8*)&Qb[(size_t)(qr0 + fr) * HDIM + s * 32 + kg];

    f32x4 o[4];
#pragma unroll
    for (int n = 0; n < 4; ++n) o[n] = (f32x4){0.f, 0.f, 0.f, 0.f};
    float mrow[4], lrow[4];
#pragma unroll
    for (int r = 0; r < 4; ++r) { mrow[r] = -1e30f; lrow[r] = 0.f; }

    const int  jlast = 2 * qt + 1;
    const bool upper = (w >= 2);  // waves 2,3: rows in q-block 2qt+1

    for (int j = 0; j <= jlast; ++j) {
        __syncthreads();  // previous iter's readers done before overwrite
        {
            // cooperative load of K tile (row-major) and V tile (transposed)
            int row = t >> 3;
            int cc  = (t & 7) * 8;
            bf16x8 kv = *(const bf16x8*)&Kb[(size_t)(j * 32 + row) * HDIM + cc];
            *(bf16x8*)&Kt[row][cc] = kv;
            bf16x8 vv = *(const bf16x8*)&Vb[(size_t)(j * 32 + row) * HDIM + cc];
#pragma unroll
            for (int e = 0; e < 8; ++e) VtT[cc + e][row] = vv[e];
        }
        __syncthreads();

        if (!upper && j == jlast) continue;  // causal: lower waves skip odd block

        // S = Q K^T  (16q x 32k): 2 col-fragments x 2 k-steps
        f32x4 sc[2];
        sc[0] = (f32x4){0.f, 0.f, 0.f, 0.f};
        sc[1] = (f32x4){0.f, 0.f, 0.f, 0.f};
#pragma unroll
        for (int st = 0; st < 2; ++st) {
#pragma unroll
            for (int n = 0; n < 2; ++n) {
                bf16x8 kb = *(const bf16x8*)&Kt[n * 16 + fr][st * 32 + kg];
                sc[n] = __builtin_amdgcn_mfma_f32_16x16x32_bf16(qa[st], kb, sc[n], 0, 0, 0);
            }
        }

        // online softmax; row r of this lane = (lane>>4)*4 + r
#pragma unroll
        for (int r = 0; r < 4; ++r) {
            float s0 = sc[0][r] * 0.125f;
            float s1 = sc[1][r] * 0.125f;
            float mx = fmaxf(s0, s1);
#pragma unroll
            for (int off = 8; off >= 1; off >>= 1)
                mx = fmaxf(mx, __shfl_xor(mx, off, 16));
            float mnew = fmaxf(mrow[r], mx);
            float fac  = __expf(mrow[r] - mnew);
            float p0   = __expf(s0 - mnew);
            float p1   = __expf(s1 - mnew);
            float ps   = p0 + p1;
#pragma unroll
            for (int off = 8; off >= 1; off >>= 1)
                ps += __shfl_xor(ps, off, 16);
            lrow[r] = lrow[r] * fac + ps;
            mrow[r] = mnew;
#pragma unroll
            for (int n = 0; n < 4; ++n) o[n][r] *= fac;

            int prow = (lane >> 4) * 4 + r;
            Pl[w][prow][fr]      = (__bf16)p0;
            Pl[w][prow][fr + 16] = (__bf16)p1;
        }

        // wave-internal LDS write->read ordering
        asm volatile("s_waitcnt lgkmcnt(0)" ::: "memory");

        // O += P V : A = P (16q x 32k), B = V^T tile (32k x 64d)
        bf16x8 pa = *(const bf16x8*)&Pl[w][fr][kg];
#pragma unroll
        for (int n = 0; n < 4; ++n) {
            bf16x8 vbf = *(const bf16x8*)&VtT[n * 16 + fr][kg];
            o[n] = __builtin_amdgcn_mfma_f32_16x16x32_bf16(pa, vbf, o[n], 0, 0, 0);
        }
    }

    // epilogue: out[b, s=row, h*64 + d] = o / l
    const int b = bh >> 4, h = bh & (NHEAD - 1);
    __bf16* ob = out + (size_t)b * S_LEN * EMB + h * HDIM;
#pragma unroll
    for (int r = 0; r < 4; ++r) {
        float inv = 1.0f / lrow[r];
        int row   = qr0 + (lane >> 4) * 4 + r;
#pragma unroll
        for (int n = 0; n < 4; ++n)
            ob[(size_t)row * EMB + n * 16 + fr] = (__bf16)(o[n][r] * inv);
    }
}

// ---------------------------------------------------------------------------
extern "C" void kernel_launch(void* const* d_in, const int* in_sizes, int n_in,
                              void* d_out, int out_size, void* d_ws, size_t ws_size,
                              hipStream_t stream) {
    const float* x  = (const float*)d_in[0];
    const float* Wq = (const float*)d_in[1];
    const float* bq = (const float*)d_in[2];
    const float* Wk = (const float*)d_in[3];
    const float* bk = (const float*)d_in[4];
    const float* Wv = (const float*)d_in[5];
    const float* bv = (const float*)d_in[6];
    const float* Wo = (const float*)d_in[7];
    const float* bo = (const float*)d_in[8];
    float* out = (float*)d_out;

    char* ws = (char*)d_ws;
    // workspace layout (bytes): all 16B-aligned
    __bf16* xb  = (__bf16*)(ws + 0);         // 4096*1024 = 8,388,608 B
    __bf16* wqb = (__bf16*)(ws + 8388608);   // 1024*1024 = 2,097,152 B
    __bf16* wkb = (__bf16*)(ws + 10485760);
    __bf16* wvb = (__bf16*)(ws + 12582912);
    __bf16* wob = (__bf16*)(ws + 14680064);
    __bf16* Qb  = (__bf16*)(ws + 16777216);  // [B,H,S,HD] bf16, 8,388,608 B
    __bf16* Kb  = (__bf16*)(ws + 25165824);
    __bf16* Vb  = (__bf16*)(ws + 33554432);
    __bf16* Ab  = (__bf16*)(ws + 41943040);  // attn out [B,S,E] bf16
    // total: 50,331,648 B

    const int M = BATCH * S_LEN;  // 4096
    const int N = EMB;            // 1024
    const int K = EMB;            // 1024

    // fp32 -> bf16 conversions
    f2b_kernel<<<(M * K / 4 + 255) / 256, 256, 0, stream>>>(x, xb, M * K / 4);
    f2b_kernel<<<(N * K / 4 + 255) / 256, 256, 0, stream>>>(Wq, wqb, N * K / 4);
    f2b_kernel<<<(N * K / 4 + 255) / 256, 256, 0, stream>>>(Wk, wkb, N * K / 4);
    f2b_kernel<<<(N * K / 4 + 255) / 256, 256, 0, stream>>>(Wv, wvb, N * K / 4);
    f2b_kernel<<<(N * K / 4 + 255) / 256, 256, 0, stream>>>(Wo, wob, N * K / 4);

    // Q/K/V projections -> [B,H,S,HD] bf16
    dim3 gg(N / 128, M / 128);
    gemm_nt<1><<<gg, 256, 0, stream>>>(xb, wqb, bq, Qb, M, N, K);
    gemm_nt<1><<<gg, 256, 0, stream>>>(xb, wkb, bk, Kb, M, N, K);
    gemm_nt<1><<<gg, 256, 0, stream>>>(xb, wvb, bv, Vb, M, N, K);

    // attention -> [B,S,E] bf16
    attn_kernel<<<dim3(S_LEN / 64, BATCH * NHEAD), 256, 0, stream>>>(Qb, Kb, Vb, Ab);

    // output projection -> fp32 d_out
    gemm_nt<0><<<gg, 256, 0, stream>>>(Ab, wob, bo, out, M, N, K);
}

// Round 2
// 168.646 us; speedup vs baseline: 1.9504x; 1.9504x over previous
//
#include <hip/hip_runtime.h>
#include <hip/hip_bf16.h>
#include <stdint.h>

#define BATCH 2
#define S_LEN 2048
#define EMB   1024
#define NHEAD 16
#define HDIM  64

typedef __attribute__((ext_vector_type(8)))  __bf16 bf16x8;
typedef __attribute__((ext_vector_type(4)))  __bf16 bf16x4;
typedef __attribute__((ext_vector_type(4)))  float  f32x4;
typedef __attribute__((ext_vector_type(16))) float  f32x16;

#define ZERO16 ((f32x16){0.f,0.f,0.f,0.f,0.f,0.f,0.f,0.f,0.f,0.f,0.f,0.f,0.f,0.f,0.f,0.f})

static __device__ __forceinline__ void gload_lds16(const void* g, void* l) {
    __builtin_amdgcn_global_load_lds(
        (__attribute__((address_space(1))) void*)g,
        (__attribute__((address_space(3))) void*)l,
        16, 0, 0);
}

// ---------------------------------------------------------------------------
// fp32 -> bf16 conversions
// ---------------------------------------------------------------------------
__global__ void f2b_kernel(const float* __restrict__ s, __bf16* __restrict__ d, int n4) {
    int i = blockIdx.x * blockDim.x + threadIdx.x;
    if (i >= n4) return;
    float4 v = reinterpret_cast<const float4*>(s)[i];
    bf16x4 o = { (__bf16)v.x, (__bf16)v.y, (__bf16)v.z, (__bf16)v.w };
    reinterpret_cast<bf16x4*>(d)[i] = o;
}

__global__ void f2b4_kernel(const float* __restrict__ s0, const float* __restrict__ s1,
                            const float* __restrict__ s2, const float* __restrict__ s3,
                            __bf16* __restrict__ d0, __bf16* __restrict__ d1,
                            __bf16* __restrict__ d2, __bf16* __restrict__ d3, int n4) {
    int i = blockIdx.x * blockDim.x + threadIdx.x;
    if (i >= n4) return;
    const float* s = blockIdx.y == 0 ? s0 : blockIdx.y == 1 ? s1 : blockIdx.y == 2 ? s2 : s3;
    __bf16*      d = blockIdx.y == 0 ? d0 : blockIdx.y == 1 ? d1 : blockIdx.y == 2 ? d2 : d3;
    float4 v = reinterpret_cast<const float4*>(s)[i];
    bf16x4 o = { (__bf16)v.x, (__bf16)v.y, (__bf16)v.z, (__bf16)v.w };
    reinterpret_cast<bf16x4*>(d)[i] = o;
}

// ---------------------------------------------------------------------------
// NT GEMM core (128x128 tile, 4 waves, 4x4 of 16x16x32), used for final proj
// ---------------------------------------------------------------------------
template <int OUT_MODE>
__global__ __launch_bounds__(256)
void gemm_nt(const __bf16* __restrict__ A, const __bf16* __restrict__ W,
             const float* __restrict__ bias, void* __restrict__ out,
             int M, int N, int K) {
    __shared__ __align__(16) __bf16 As[128 * 32];
    __shared__ __align__(16) __bf16 Bs[128 * 32];

    const int t    = threadIdx.x;
    const int w    = t >> 6;
    const int lane = t & 63;
    const int m0   = blockIdx.y * 128;
    const int n0   = blockIdx.x * 128;
    const int wr   = (w >> 1) * 64;
    const int wc   = (w & 1) * 64;
    const int fr   = lane & 15;
    const int kg   = (lane >> 4) * 8;

    f32x4 acc[4][4];
#pragma unroll
    for (int i = 0; i < 4; ++i)
#pragma unroll
        for (int j = 0; j < 4; ++j) acc[i][j] = (f32x4){0.f, 0.f, 0.f, 0.f};

    for (int kt = 0; kt < K; kt += 32) {
#pragma unroll
        for (int i = 0; i < 2; ++i) {
            int chunk = i * 256 + t;
            int row   = chunk >> 2;
            int col   = (chunk & 3) * 8;
            gload_lds16(A + (size_t)(m0 + row) * K + kt + col,
                        (char*)As + i * 4096 + w * 1024);
            gload_lds16(W + (size_t)(n0 + row) * K + kt + col,
                        (char*)Bs + i * 4096 + w * 1024);
        }
        __syncthreads();

        bf16x8 af[4], bfv[4];
#pragma unroll
        for (int m = 0; m < 4; ++m)
            af[m] = *(const bf16x8*)&As[(wr + m * 16 + fr) * 32 + kg];
#pragma unroll
        for (int n = 0; n < 4; ++n)
            bfv[n] = *(const bf16x8*)&Bs[(wc + n * 16 + fr) * 32 + kg];
#pragma unroll
        for (int m = 0; m < 4; ++m)
#pragma unroll
            for (int n = 0; n < 4; ++n)
                acc[m][n] = __builtin_amdgcn_mfma_f32_16x16x32_bf16(
                    af[m], bfv[n], acc[m][n], 0, 0, 0);
        __syncthreads();
    }

    const int rbase = (lane >> 4) * 4;
#pragma unroll
    for (int m = 0; m < 4; ++m) {
#pragma unroll
        for (int n = 0; n < 4; ++n) {
            int col  = n0 + wc + n * 16 + fr;
            float bv = bias[col];
#pragma unroll
            for (int j = 0; j < 4; ++j) {
                int row = m0 + wr + m * 16 + rbase + j;
                float v = acc[m][n][j] + bv;
                if (OUT_MODE == 0) {
                    ((float*)out)[(size_t)row * N + col] = v;
                } else {
                    int b = row >> 11, s = row & (S_LEN - 1);
                    int h = col >> 6,  d = col & (HDIM - 1);
                    ((__bf16*)out)[(((size_t)(b * NHEAD + h)) * S_LEN + s) * HDIM + d] =
                        (__bf16)v;
                }
            }
        }
    }
}

// ---------------------------------------------------------------------------
// Fused QKV projection: 3 NT GEMMs in one grid; which = blockIdx.x>>3
// ---------------------------------------------------------------------------
__global__ __launch_bounds__(256)
void gemm_qkv(const __bf16* __restrict__ A,
              const __bf16* __restrict__ W0p, const __bf16* __restrict__ W1p,
              const __bf16* __restrict__ W2p,
              const float* __restrict__ b0p, const float* __restrict__ b1p,
              const float* __restrict__ b2p,
              __bf16* __restrict__ o0, __bf16* __restrict__ o1,
              __bf16* __restrict__ o2, int M, int N, int K) {
    __shared__ __align__(16) __bf16 As[128 * 32];
    __shared__ __align__(16) __bf16 Bs[128 * 32];

    const int which = blockIdx.x >> 3;
    const __bf16* W    = which == 0 ? W0p : which == 1 ? W1p : W2p;
    const float*  bias = which == 0 ? b0p : which == 1 ? b1p : b2p;
    __bf16*       out  = which == 0 ? o0  : which == 1 ? o1  : o2;

    const int t    = threadIdx.x;
    const int w    = t >> 6;
    const int lane = t & 63;
    const int m0   = blockIdx.y * 128;
    const int n0   = (blockIdx.x & 7) * 128;
    const int wr   = (w >> 1) * 64;
    const int wc   = (w & 1) * 64;
    const int fr   = lane & 15;
    const int kg   = (lane >> 4) * 8;

    f32x4 acc[4][4];
#pragma unroll
    for (int i = 0; i < 4; ++i)
#pragma unroll
        for (int j = 0; j < 4; ++j) acc[i][j] = (f32x4){0.f, 0.f, 0.f, 0.f};

    for (int kt = 0; kt < K; kt += 32) {
#pragma unroll
        for (int i = 0; i < 2; ++i) {
            int chunk = i * 256 + t;
            int row   = chunk >> 2;
            int col   = (chunk & 3) * 8;
            gload_lds16(A + (size_t)(m0 + row) * K + kt + col,
                        (char*)As + i * 4096 + w * 1024);
            gload_lds16(W + (size_t)(n0 + row) * K + kt + col,
                        (char*)Bs + i * 4096 + w * 1024);
        }
        __syncthreads();

        bf16x8 af[4], bfv[4];
#pragma unroll
        for (int m = 0; m < 4; ++m)
            af[m] = *(const bf16x8*)&As[(wr + m * 16 + fr) * 32 + kg];
#pragma unroll
        for (int n = 0; n < 4; ++n)
            bfv[n] = *(const bf16x8*)&Bs[(wc + n * 16 + fr) * 32 + kg];
#pragma unroll
        for (int m = 0; m < 4; ++m)
#pragma unroll
            for (int n = 0; n < 4; ++n)
                acc[m][n] = __builtin_amdgcn_mfma_f32_16x16x32_bf16(
                    af[m], bfv[n], acc[m][n], 0, 0, 0);
        __syncthreads();
    }

    const int rbase = (lane >> 4) * 4;
#pragma unroll
    for (int m = 0; m < 4; ++m) {
#pragma unroll
        for (int n = 0; n < 4; ++n) {
            int col  = n0 + wc + n * 16 + fr;
            float bv = bias[col];
#pragma unroll
            for (int j = 0; j < 4; ++j) {
                int row = m0 + wr + m * 16 + rbase + j;
                float v = acc[m][n][j] + bv;
                int b = row >> 11, s = row & (S_LEN - 1);
                int h = col >> 6,  d = col & (HDIM - 1);
                out[(((size_t)(b * NHEAD + h)) * S_LEN + s) * HDIM + d] = (__bf16)v;
            }
        }
    }
}

// ---------------------------------------------------------------------------
// Block-causal flash attention, swapped-QK^T 32x32 structure.
// Block: 256 thr = 4 waves; q-tile 128 (wave w owns 32 q-rows = q-block 4qt+w).
// KV chunk 64 (2 causal sub-blocks of 32, predicated per wave). Double-buffered
// K (global_load_lds, XOR-swizzled src) and V^T (reg transpose, XOR-swizzled).
// Softmax per-lane (lane&31 = q-row), pair-combined via shfl_xor(32).
// ---------------------------------------------------------------------------
__global__ __launch_bounds__(256)
void attn2_kernel(const __bf16* __restrict__ Q, const __bf16* __restrict__ Kv,
                  const __bf16* __restrict__ V, __bf16* __restrict__ out) {
    __shared__ __align__(16) __bf16 Kt[2][64 * 64];   // [key][d^((key&7)<<3)]
    __shared__ __align__(16) __bf16 Vt[2][64 * 64];   // [d][key^((d&7)<<3)]
    __shared__ float bc[4][32];

    const int t    = threadIdx.x;
    const int w    = t >> 6;
    const int lane = t & 63;
    const int h    = lane >> 5;
    const int q32  = lane & 31;
    const int qt   = blockIdx.x;
    const int bh   = blockIdx.y;

    const __bf16* Qp = Q  + (size_t)bh * S_LEN * HDIM;
    const __bf16* Kp = Kv + (size_t)bh * S_LEN * HDIM;
    const __bf16* Vp = V  + (size_t)bh * S_LEN * HDIM;

    const int myqblk = 4 * qt + w;            // max allowed kv-block (BLK=32)
    const int qrow   = qt * 128 + w * 32 + q32;

    // Q fragments (B-operand of S^T mfma): col=q32, k=d=16ks+8h+e
    bf16x8 qreg[4];
#pragma unroll
    for (int ks = 0; ks < 4; ++ks)
        qreg[ks] = *(const bf16x8*)&Qp[(size_t)qrow * HDIM + 16 * ks + 8 * h];

    f32x16 oacc0 = ZERO16, oacc1 = ZERO16;    // O cols d=q32 / 32+q32
    float mrun = -1e30f, lrun = 0.f;

    const int nch = 2 * qt + 2;

    // ---- prologue: stage chunk 0 ----
    {
#pragma unroll
        for (int i = 0; i < 2; ++i) {
            int c16 = i * 256 + t;
            int key = c16 >> 3;
            int d0  = ((c16 & 7) ^ (key & 7)) * 8;
            gload_lds16(Kp + (size_t)key * HDIM + d0, (char*)&Kt[0][0] + c16 * 16);
        }
        bf16x8 vr[2];
#pragma unroll
        for (int i = 0; i < 2; ++i)
            vr[i] = *(const bf16x8*)&Vp[(size_t)lane * HDIM + (4 * i + w) * 8];
#pragma unroll
        for (int i = 0; i < 2; ++i) {
            int d0 = (4 * i + w) * 8;
#pragma unroll
            for (int e = 0; e < 8; ++e)
                Vt[0][(d0 + e) * 64 + (lane ^ (e << 3))] = vr[i][e];
        }
        __syncthreads();
    }

    for (int c = 0; c < nch; ++c) {
        const int cur = c & 1;
        const bool pre = (c + 1 < nch);
        bf16x8 vr[2];
        if (pre) {
            const int kb = (c + 1) * 64;
#pragma unroll
            for (int i = 0; i < 2; ++i) {
                int c16 = i * 256 + t;
                int key = c16 >> 3;
                int d0  = ((c16 & 7) ^ (key & 7)) * 8;
                gload_lds16(Kp + (size_t)(kb + key) * HDIM + d0,
                            (char*)&Kt[cur ^ 1][0] + c16 * 16);
            }
#pragma unroll
            for (int i = 0; i < 2; ++i)
                vr[i] = *(const bf16x8*)&Vp[(size_t)(kb + lane) * HDIM + (4 * i + w) * 8];
        }

#pragma unroll
        for (int u = 0; u < 2; ++u) {
            if (2 * c + u > myqblk) break;   // causal skip (wave-uniform)

            // S^T = K . Q^T  (rows=key, cols=q)
            f32x16 sac = ZERO16;
#pragma unroll
            for (int ks = 0; ks < 4; ++ks) {
                bf16x8 kf = *(const bf16x8*)&Kt[cur][(32 * u + q32) * 64 +
                                ((16 * ks + 8 * h) ^ ((q32 & 7) << 3))];
                sac = __builtin_amdgcn_mfma_f32_32x32x16_bf16(kf, qreg[ks], sac, 0, 0, 0);
            }

            // per-lane softmax over 16 regs; combine with partner lane^32
            float s[16], p[16];
#pragma unroll
            for (int r = 0; r < 16; ++r) s[r] = sac[r] * 0.125f;
            float pmax = s[0];
#pragma unroll
            for (int r = 1; r < 16; ++r) pmax = fmaxf(pmax, s[r]);
            pmax = fmaxf(pmax, __shfl_xor(pmax, 32));
            float mnew = fmaxf(mrun, pmax);
            float fac  = __expf(mrun - mnew);
            float ps = 0.f;
#pragma unroll
            for (int r = 0; r < 16; ++r) { p[r] = __expf(s[r] - mnew); ps += p[r]; }
            ps += __shfl_xor(ps, 32);
            lrun = lrun * fac + ps;
            mrun = mnew;

            // broadcast fac by q-row, rescale O
            bc[w][q32] = fac;
            asm volatile("s_waitcnt lgkmcnt(0)" ::: "memory");
            __builtin_amdgcn_sched_barrier(0);
#pragma unroll
            for (int q2 = 0; q2 < 4; ++q2) {
                f32x4 fv = *(const f32x4*)&bc[w][8 * q2 + 4 * h];
#pragma unroll
                for (int j = 0; j < 4; ++j) {
                    oacc0[4 * q2 + j] *= fv[j];
                    oacc1[4 * q2 + j] *= fv[j];
                }
            }

            // pack P rows to bf16 words: L[g]=rows(8g+4h)+{0,1}, H[g]=+{2,3}
            unsigned L[4], H[4];
#pragma unroll
            for (int g = 0; g < 4; ++g) {
                __bf16 b0 = (__bf16)p[4 * g],     b1 = (__bf16)p[4 * g + 1];
                __bf16 b2 = (__bf16)p[4 * g + 2], b3 = (__bf16)p[4 * g + 3];
                L[g] = (unsigned)*(unsigned short*)&b0 |
                       ((unsigned)*(unsigned short*)&b1 << 16);
                H[g] = (unsigned)*(unsigned short*)&b2 |
                       ((unsigned)*(unsigned short*)&b3 << 16);
            }

#pragma unroll
            for (int s2 = 0; s2 < 2; ++s2) {
                unsigned Lo = L[2 * s2], Lp = L[2 * s2 + 1];
                unsigned Ho = H[2 * s2], Hp = H[2 * s2 + 1];
                unsigned sLp = (unsigned)__shfl_xor((int)Lp, 32);
                unsigned sLo = (unsigned)__shfl_xor((int)Lo, 32);
                unsigned sHp = (unsigned)__shfl_xor((int)Hp, 32);
                unsigned sHo = (unsigned)__shfl_xor((int)Ho, 32);
                unsigned wv[4];
                wv[0] = h ? sLp : Lo;   // keys 16s2+8h+{0,1}
                wv[1] = h ? sHp : Ho;   // +{2,3}
                wv[2] = h ? Lp  : sLo;  // +{4,5}
                wv[3] = h ? Hp  : sHo;  // +{6,7}
                bf16x8 pa = *(bf16x8*)wv;

                const int kwb = 32 * u + 16 * s2;
#pragma unroll
                for (int n = 0; n < 2; ++n) {
                    int d = 32 * n + q32;
                    bf16x8 vf = *(const bf16x8*)&Vt[cur][d * 64 +
                                    ((kwb + 8 * h) ^ ((d & 7) << 3))];
                    if (n == 0)
                        oacc0 = __builtin_amdgcn_mfma_f32_32x32x16_bf16(pa, vf, oacc0, 0, 0, 0);
                    else
                        oacc1 = __builtin_amdgcn_mfma_f32_32x32x16_bf16(pa, vf, oacc1, 0, 0, 0);
                }
            }
        }

        if (pre) {
            const int buf = cur ^ 1;
#pragma unroll
            for (int i = 0; i < 2; ++i) {
                int d0 = (4 * i + w) * 8;
#pragma unroll
                for (int e = 0; e < 8; ++e)
                    Vt[buf][(d0 + e) * 64 + (lane ^ (e << 3))] = vr[i][e];
            }
        }
        __syncthreads();
    }

    // ---- epilogue ----
    bc[w][q32] = lrun;
    asm volatile("s_waitcnt lgkmcnt(0)" ::: "memory");
    __builtin_amdgcn_sched_barrier(0);
    const int b = bh >> 4, hh = bh & (NHEAD - 1);
    __bf16* op = out + (size_t)b * S_LEN * EMB + hh * HDIM;
#pragma unroll
    for (int q2 = 0; q2 < 4; ++q2) {
        f32x4 lv = *(const f32x4*)&bc[w][8 * q2 + 4 * h];
#pragma unroll
        for (int j = 0; j < 4; ++j) {
            int r   = 4 * q2 + j;
            int row = qt * 128 + w * 32 + 8 * q2 + 4 * h + j;
            float inv = 1.f / lv[j];
            op[(size_t)row * EMB + q32]      = (__bf16)(oacc0[r] * inv);
            op[(size_t)row * EMB + 32 + q32] = (__bf16)(oacc1[r] * inv);
        }
    }
}

// ---------------------------------------------------------------------------
extern "C" void kernel_launch(void* const* d_in, const int* in_sizes, int n_in,
                              void* d_out, int out_size, void* d_ws, size_t ws_size,
                              hipStream_t stream) {
    const float* x  = (const float*)d_in[0];
    const float* Wq = (const float*)d_in[1];
    const float* bq = (const float*)d_in[2];
    const float* Wk = (const float*)d_in[3];
    const float* bk = (const float*)d_in[4];
    const float* Wv = (const float*)d_in[5];
    const float* bv = (const float*)d_in[6];
    const float* Wo = (const float*)d_in[7];
    const float* bo = (const float*)d_in[8];
    float* out = (float*)d_out;

    char* ws = (char*)d_ws;
    __bf16* xb  = (__bf16*)(ws + 0);
    __bf16* wqb = (__bf16*)(ws + 8388608);
    __bf16* wkb = (__bf16*)(ws + 10485760);
    __bf16* wvb = (__bf16*)(ws + 12582912);
    __bf16* wob = (__bf16*)(ws + 14680064);
    __bf16* Qb  = (__bf16*)(ws + 16777216);
    __bf16* Kb  = (__bf16*)(ws + 25165824);
    __bf16* Vb  = (__bf16*)(ws + 33554432);
    __bf16* Ab  = (__bf16*)(ws + 41943040);

    const int M = BATCH * S_LEN;  // 4096
    const int N = EMB;            // 1024
    const int K = EMB;            // 1024

    f2b_kernel<<<(M * K / 4 + 255) / 256, 256, 0, stream>>>(x, xb, M * K / 4);
    f2b4_kernel<<<dim3(N * K / 4 / 256, 4), 256, 0, stream>>>(
        Wq, Wk, Wv, Wo, wqb, wkb, wvb, wob, N * K / 4);

    gemm_qkv<<<dim3(24, M / 128), 256, 0, stream>>>(
        xb, wqb, wkb, wvb, bq, bk, bv, Qb, Kb, Vb, M, N, K);

    attn2_kernel<<<dim3(S_LEN / 128, BATCH * NHEAD), 256, 0, stream>>>(Qb, Kb, Vb, Ab);

    gemm_nt<0><<<dim3(N / 128, M / 128), 256, 0, stream>>>(Ab, wob, bo, out, M, N, K);
}

// Round 3
// 156.083 us; speedup vs baseline: 2.1074x; 1.0805x over previous
//
#include <hip/hip_runtime.h>
#include <hip/hip_bf16.h>
#include <stdint.h>

#define BATCH 2
#define S_LEN 2048
#define EMB   1024
#define NHEAD 16
#define HDIM  64

typedef __attribute__((ext_vector_type(8)))  __bf16 bf16x8;
typedef __attribute__((ext_vector_type(4)))  __bf16 bf16x4;
typedef __attribute__((ext_vector_type(4)))  float  f32x4;
typedef __attribute__((ext_vector_type(16))) float  f32x16;

#define ZERO16 ((f32x16){0.f,0.f,0.f,0.f,0.f,0.f,0.f,0.f,0.f,0.f,0.f,0.f,0.f,0.f,0.f,0.f})
#define SM_SCALE_LOG2 0.18033688011112042f  /* 0.125 * log2(e) */

static __device__ __forceinline__ void gload_lds16(const void* g, void* l) {
    __builtin_amdgcn_global_load_lds(
        (__attribute__((address_space(1))) void*)g,
        (__attribute__((address_space(3))) void*)l,
        16, 0, 0);
}

// ---------------------------------------------------------------------------
// fp32 -> bf16 conversions
// ---------------------------------------------------------------------------
__global__ void f2b_kernel(const float* __restrict__ s, __bf16* __restrict__ d, int n4) {
    int i = blockIdx.x * blockDim.x + threadIdx.x;
    if (i >= n4) return;
    float4 v = reinterpret_cast<const float4*>(s)[i];
    bf16x4 o = { (__bf16)v.x, (__bf16)v.y, (__bf16)v.z, (__bf16)v.w };
    reinterpret_cast<bf16x4*>(d)[i] = o;
}

__global__ void f2b4_kernel(const float* __restrict__ s0, const float* __restrict__ s1,
                            const float* __restrict__ s2, const float* __restrict__ s3,
                            __bf16* __restrict__ d0, __bf16* __restrict__ d1,
                            __bf16* __restrict__ d2, __bf16* __restrict__ d3, int n4) {
    int i = blockIdx.x * blockDim.x + threadIdx.x;
    if (i >= n4) return;
    const float* s = blockIdx.y == 0 ? s0 : blockIdx.y == 1 ? s1 : blockIdx.y == 2 ? s2 : s3;
    __bf16*      d = blockIdx.y == 0 ? d0 : blockIdx.y == 1 ? d1 : blockIdx.y == 2 ? d2 : d3;
    float4 v = reinterpret_cast<const float4*>(s)[i];
    bf16x4 o = { (__bf16)v.x, (__bf16)v.y, (__bf16)v.z, (__bf16)v.w };
    reinterpret_cast<bf16x4*>(d)[i] = o;
}

// ---------------------------------------------------------------------------
// NT GEMM core (128x128 tile, 4 waves, 4x4 of 16x16x32), used for final proj
// ---------------------------------------------------------------------------
template <int OUT_MODE>
__global__ __launch_bounds__(256)
void gemm_nt(const __bf16* __restrict__ A, const __bf16* __restrict__ W,
             const float* __restrict__ bias, void* __restrict__ out,
             int M, int N, int K) {
    __shared__ __align__(16) __bf16 As[128 * 32];
    __shared__ __align__(16) __bf16 Bs[128 * 32];

    const int t    = threadIdx.x;
    const int w    = t >> 6;
    const int lane = t & 63;
    const int m0   = blockIdx.y * 128;
    const int n0   = blockIdx.x * 128;
    const int wr   = (w >> 1) * 64;
    const int wc   = (w & 1) * 64;
    const int fr   = lane & 15;
    const int kg   = (lane >> 4) * 8;

    f32x4 acc[4][4];
#pragma unroll
    for (int i = 0; i < 4; ++i)
#pragma unroll
        for (int j = 0; j < 4; ++j) acc[i][j] = (f32x4){0.f, 0.f, 0.f, 0.f};

    for (int kt = 0; kt < K; kt += 32) {
#pragma unroll
        for (int i = 0; i < 2; ++i) {
            int chunk = i * 256 + t;
            int row   = chunk >> 2;
            int col   = (chunk & 3) * 8;
            gload_lds16(A + (size_t)(m0 + row) * K + kt + col,
                        (char*)As + i * 4096 + w * 1024);
            gload_lds16(W + (size_t)(n0 + row) * K + kt + col,
                        (char*)Bs + i * 4096 + w * 1024);
        }
        __syncthreads();

        bf16x8 af[4], bfv[4];
#pragma unroll
        for (int m = 0; m < 4; ++m)
            af[m] = *(const bf16x8*)&As[(wr + m * 16 + fr) * 32 + kg];
#pragma unroll
        for (int n = 0; n < 4; ++n)
            bfv[n] = *(const bf16x8*)&Bs[(wc + n * 16 + fr) * 32 + kg];
#pragma unroll
        for (int m = 0; m < 4; ++m)
#pragma unroll
            for (int n = 0; n < 4; ++n)
                acc[m][n] = __builtin_amdgcn_mfma_f32_16x16x32_bf16(
                    af[m], bfv[n], acc[m][n], 0, 0, 0);
        __syncthreads();
    }

    const int rbase = (lane >> 4) * 4;
#pragma unroll
    for (int m = 0; m < 4; ++m) {
#pragma unroll
        for (int n = 0; n < 4; ++n) {
            int col  = n0 + wc + n * 16 + fr;
            float bv = bias[col];
#pragma unroll
            for (int j = 0; j < 4; ++j) {
                int row = m0 + wr + m * 16 + rbase + j;
                float v = acc[m][n][j] + bv;
                if (OUT_MODE == 0) {
                    ((float*)out)[(size_t)row * N + col] = v;
                } else {
                    int b = row >> 11, s = row & (S_LEN - 1);
                    int h = col >> 6,  d = col & (HDIM - 1);
                    ((__bf16*)out)[(((size_t)(b * NHEAD + h)) * S_LEN + s) * HDIM + d] =
                        (__bf16)v;
                }
            }
        }
    }
}

// ---------------------------------------------------------------------------
// Fused QKV projection: 3 NT GEMMs in one grid; which = blockIdx.x>>3
// ---------------------------------------------------------------------------
__global__ __launch_bounds__(256)
void gemm_qkv(const __bf16* __restrict__ A,
              const __bf16* __restrict__ W0p, const __bf16* __restrict__ W1p,
              const __bf16* __restrict__ W2p,
              const float* __restrict__ b0p, const float* __restrict__ b1p,
              const float* __restrict__ b2p,
              __bf16* __restrict__ o0, __bf16* __restrict__ o1,
              __bf16* __restrict__ o2, int M, int N, int K) {
    __shared__ __align__(16) __bf16 As[128 * 32];
    __shared__ __align__(16) __bf16 Bs[128 * 32];

    const int which = blockIdx.x >> 3;
    const __bf16* W    = which == 0 ? W0p : which == 1 ? W1p : W2p;
    const float*  bias = which == 0 ? b0p : which == 1 ? b1p : b2p;
    __bf16*       out  = which == 0 ? o0  : which == 1 ? o1  : o2;

    const int t    = threadIdx.x;
    const int w    = t >> 6;
    const int lane = t & 63;
    const int m0   = blockIdx.y * 128;
    const int n0   = (blockIdx.x & 7) * 128;
    const int wr   = (w >> 1) * 64;
    const int wc   = (w & 1) * 64;
    const int fr   = lane & 15;
    const int kg   = (lane >> 4) * 8;

    f32x4 acc[4][4];
#pragma unroll
    for (int i = 0; i < 4; ++i)
#pragma unroll
        for (int j = 0; j < 4; ++j) acc[i][j] = (f32x4){0.f, 0.f, 0.f, 0.f};

    for (int kt = 0; kt < K; kt += 32) {
#pragma unroll
        for (int i = 0; i < 2; ++i) {
            int chunk = i * 256 + t;
            int row   = chunk >> 2;
            int col   = (chunk & 3) * 8;
            gload_lds16(A + (size_t)(m0 + row) * K + kt + col,
                        (char*)As + i * 4096 + w * 1024);
            gload_lds16(W + (size_t)(n0 + row) * K + kt + col,
                        (char*)Bs + i * 4096 + w * 1024);
        }
        __syncthreads();

        bf16x8 af[4], bfv[4];
#pragma unroll
        for (int m = 0; m < 4; ++m)
            af[m] = *(const bf16x8*)&As[(wr + m * 16 + fr) * 32 + kg];
#pragma unroll
        for (int n = 0; n < 4; ++n)
            bfv[n] = *(const bf16x8*)&Bs[(wc + n * 16 + fr) * 32 + kg];
#pragma unroll
        for (int m = 0; m < 4; ++m)
#pragma unroll
            for (int n = 0; n < 4; ++n)
                acc[m][n] = __builtin_amdgcn_mfma_f32_16x16x32_bf16(
                    af[m], bfv[n], acc[m][n], 0, 0, 0);
        __syncthreads();
    }

    const int rbase = (lane >> 4) * 4;
#pragma unroll
    for (int m = 0; m < 4; ++m) {
#pragma unroll
        for (int n = 0; n < 4; ++n) {
            int col  = n0 + wc + n * 16 + fr;
            float bv = bias[col];
#pragma unroll
            for (int j = 0; j < 4; ++j) {
                int row = m0 + wr + m * 16 + rbase + j;
                float v = acc[m][n][j] + bv;
                int b = row >> 11, s = row & (S_LEN - 1);
                int h = col >> 6,  d = col & (HDIM - 1);
                out[(((size_t)(b * NHEAD + h)) * S_LEN + s) * HDIM + d] = (__bf16)v;
            }
        }
    }
}

// ---------------------------------------------------------------------------
// Block-causal flash attention, swapped-QK^T 32x32 structure.
// Grid: (x=bh, y=qt) so linear id % 8 = bh % 8 -> every XCD sees all qt
// values (uniform inter-XCD work); a CU's 2 co-resident blocks form a
// (qt, qt+8) complementary pair.
// Block: 256 thr = 4 waves; q-tile 128 (wave w owns q-block 4qt+w of 32 rows).
// KV chunk 64 (2 causal sub-blocks of 32, predicated per wave). Double-buffered
// K (global_load_lds, XOR-swizzled src) and V^T (reg transpose, XOR-swizzled).
// Softmax per-lane in exp2 domain; pair-combine via shfl_xor(32); P exchange
// via v_permlane32_swap_b32; defer-max rescale (THR=8).
// ---------------------------------------------------------------------------
__global__ __launch_bounds__(256)
void attn2_kernel(const __bf16* __restrict__ Q, const __bf16* __restrict__ Kv,
                  const __bf16* __restrict__ V, __bf16* __restrict__ out) {
    __shared__ __align__(16) __bf16 Kt[2][64 * 64];   // [key][d^((key&7)<<3)]
    __shared__ __align__(16) __bf16 Vt[2][64 * 64];   // [d][key^((d&7)<<3)]
    __shared__ float bc[4][32];

    const int t    = threadIdx.x;
    const int w    = t >> 6;
    const int lane = t & 63;
    const int h    = lane >> 5;
    const int q32  = lane & 31;
    const int bh   = blockIdx.x;   // 0..31
    const int qt   = blockIdx.y;   // 0..15

    const __bf16* Qp = Q  + (size_t)bh * S_LEN * HDIM;
    const __bf16* Kp = Kv + (size_t)bh * S_LEN * HDIM;
    const __bf16* Vp = V  + (size_t)bh * S_LEN * HDIM;

    const int myqblk = 4 * qt + w;            // max allowed kv-block (BLK=32)
    const int qrow   = qt * 128 + w * 32 + q32;

    // Q fragments (B-operand of S^T mfma): col=q32, k=d=16ks+8h+e
    bf16x8 qreg[4];
#pragma unroll
    for (int ks = 0; ks < 4; ++ks)
        qreg[ks] = *(const bf16x8*)&Qp[(size_t)qrow * HDIM + 16 * ks + 8 * h];

    f32x16 oacc0 = ZERO16, oacc1 = ZERO16;    // O cols d=q32 / 32+q32
    float mrun = -1e30f, lrun = 0.f;          // log2-domain running max

    const int nch = 2 * qt + 2;

    // ---- prologue: stage chunk 0 ----
    {
#pragma unroll
        for (int i = 0; i < 2; ++i) {
            int c16 = i * 256 + t;
            int key = c16 >> 3;
            int d0  = ((c16 & 7) ^ (key & 7)) * 8;
            gload_lds16(Kp + (size_t)key * HDIM + d0, (char*)&Kt[0][0] + c16 * 16);
        }
        bf16x8 vr[2];
#pragma unroll
        for (int i = 0; i < 2; ++i)
            vr[i] = *(const bf16x8*)&Vp[(size_t)lane * HDIM + (4 * i + w) * 8];
#pragma unroll
        for (int i = 0; i < 2; ++i) {
            int d0 = (4 * i + w) * 8;
#pragma unroll
            for (int e = 0; e < 8; ++e)
                Vt[0][(d0 + e) * 64 + (lane ^ (e << 3))] = vr[i][e];
        }
        __syncthreads();
    }

    for (int c = 0; c < nch; ++c) {
        const int cur = c & 1;
        const bool pre = (c + 1 < nch);
        bf16x8 vr[2];
        if (pre) {
            const int kb = (c + 1) * 64;
#pragma unroll
            for (int i = 0; i < 2; ++i) {
                int c16 = i * 256 + t;
                int key = c16 >> 3;
                int d0  = ((c16 & 7) ^ (key & 7)) * 8;
                gload_lds16(Kp + (size_t)(kb + key) * HDIM + d0,
                            (char*)&Kt[cur ^ 1][0] + c16 * 16);
            }
#pragma unroll
            for (int i = 0; i < 2; ++i)
                vr[i] = *(const bf16x8*)&Vp[(size_t)(kb + lane) * HDIM + (4 * i + w) * 8];
        }

#pragma unroll
        for (int u = 0; u < 2; ++u) {
            if (2 * c + u > myqblk) break;   // causal skip (wave-uniform)

            // S^T = K . Q^T  (rows=key, cols=q)
            f32x16 sac = ZERO16;
#pragma unroll
            for (int ks = 0; ks < 4; ++ks) {
                bf16x8 kf = *(const bf16x8*)&Kt[cur][(32 * u + q32) * 64 +
                                ((16 * ks + 8 * h) ^ ((q32 & 7) << 3))];
                sac = __builtin_amdgcn_mfma_f32_32x32x16_bf16(kf, qreg[ks], sac, 0, 0, 0);
            }

            // per-lane softmax (log2 domain) over 16 regs; combine lane^32
            float s[16], p[16];
#pragma unroll
            for (int r = 0; r < 16; ++r) s[r] = sac[r] * SM_SCALE_LOG2;
            float pmax = s[0];
#pragma unroll
            for (int r = 1; r < 16; ++r) pmax = fmaxf(pmax, s[r]);
            pmax = fmaxf(pmax, __shfl_xor(pmax, 32));

            // defer-max: rescale only when the running max grew by > 8
            if (__any(pmax > mrun + 8.f)) {
                float mnew = fmaxf(mrun, pmax);
                float fac  = exp2f(mrun - mnew);
                mrun = mnew;
                lrun *= fac;
                bc[w][q32] = fac;
                asm volatile("s_waitcnt lgkmcnt(0)" ::: "memory");
                __builtin_amdgcn_sched_barrier(0);
#pragma unroll
                for (int q2 = 0; q2 < 4; ++q2) {
                    f32x4 fv = *(const f32x4*)&bc[w][8 * q2 + 4 * h];
#pragma unroll
                    for (int j = 0; j < 4; ++j) {
                        oacc0[4 * q2 + j] *= fv[j];
                        oacc1[4 * q2 + j] *= fv[j];
                    }
                }
            }

            float ps = 0.f;
#pragma unroll
            for (int r = 0; r < 16; ++r) { p[r] = exp2f(s[r] - mrun); ps += p[r]; }
            ps += __shfl_xor(ps, 32);
            lrun += ps;

            // pack P rows to bf16 words: L[g]=rows(8g+4h)+{0,1}, H[g]=+{2,3}
            unsigned L[4], H[4];
#pragma unroll
            for (int g = 0; g < 4; ++g) {
                __bf16 b0 = (__bf16)p[4 * g],     b1 = (__bf16)p[4 * g + 1];
                __bf16 b2 = (__bf16)p[4 * g + 2], b3 = (__bf16)p[4 * g + 3];
                L[g] = (unsigned)*(unsigned short*)&b0 |
                       ((unsigned)*(unsigned short*)&b1 << 16);
                H[g] = (unsigned)*(unsigned short*)&b2 |
                       ((unsigned)*(unsigned short*)&b3 << 16);
            }

#pragma unroll
            for (int s2 = 0; s2 < 2; ++s2) {
                // one permlane32_swap yields BOTH needed words:
                // A' = {lo: own-L, hi: partner-L}, B' = {lo: partner-L, hi: own-L}
                unsigned a0 = L[2 * s2], b0 = L[2 * s2 + 1];
                unsigned a1 = H[2 * s2], b1 = H[2 * s2 + 1];
                asm("v_permlane32_swap_b32 %0, %1" : "+v"(a0), "+v"(b0));
                asm("v_permlane32_swap_b32 %0, %1" : "+v"(a1), "+v"(b1));
                unsigned wvw[4] = { a0, a1, b0, b1 };
                bf16x8 pa = *(bf16x8*)wvw;

                const int kwb = 32 * u + 16 * s2;
#pragma unroll
                for (int n = 0; n < 2; ++n) {
                    int d = 32 * n + q32;
                    bf16x8 vf = *(const bf16x8*)&Vt[cur][d * 64 +
                                    ((kwb + 8 * h) ^ ((d & 7) << 3))];
                    if (n == 0)
                        oacc0 = __builtin_amdgcn_mfma_f32_32x32x16_bf16(pa, vf, oacc0, 0, 0, 0);
                    else
                        oacc1 = __builtin_amdgcn_mfma_f32_32x32x16_bf16(pa, vf, oacc1, 0, 0, 0);
                }
            }
        }

        if (pre) {
            const int buf = cur ^ 1;
#pragma unroll
            for (int i = 0; i < 2; ++i) {
                int d0 = (4 * i + w) * 8;
#pragma unroll
                for (int e = 0; e < 8; ++e)
                    Vt[buf][(d0 + e) * 64 + (lane ^ (e << 3))] = vr[i][e];
            }
        }
        __syncthreads();
    }

    // ---- epilogue ----
    bc[w][q32] = lrun;
    asm volatile("s_waitcnt lgkmcnt(0)" ::: "memory");
    __builtin_amdgcn_sched_barrier(0);
    const int b = bh >> 4, hh = bh & (NHEAD - 1);
    __bf16* op = out + (size_t)b * S_LEN * EMB + hh * HDIM;
#pragma unroll
    for (int q2 = 0; q2 < 4; ++q2) {
        f32x4 lv = *(const f32x4*)&bc[w][8 * q2 + 4 * h];
#pragma unroll
        for (int j = 0; j < 4; ++j) {
            int r   = 4 * q2 + j;
            int row = qt * 128 + w * 32 + 8 * q2 + 4 * h + j;
            float inv = 1.f / lv[j];
            op[(size_t)row * EMB + q32]      = (__bf16)(oacc0[r] * inv);
            op[(size_t)row * EMB + 32 + q32] = (__bf16)(oacc1[r] * inv);
        }
    }
}

// ---------------------------------------------------------------------------
extern "C" void kernel_launch(void* const* d_in, const int* in_sizes, int n_in,
                              void* d_out, int out_size, void* d_ws, size_t ws_size,
                              hipStream_t stream) {
    const float* x  = (const float*)d_in[0];
    const float* Wq = (const float*)d_in[1];
    const float* bq = (const float*)d_in[2];
    const float* Wk = (const float*)d_in[3];
    const float* bk = (const float*)d_in[4];
    const float* Wv = (const float*)d_in[5];
    const float* bv = (const float*)d_in[6];
    const float* Wo = (const float*)d_in[7];
    const float* bo = (const float*)d_in[8];
    float* out = (float*)d_out;

    char* ws = (char*)d_ws;
    __bf16* xb  = (__bf16*)(ws + 0);
    __bf16* wqb = (__bf16*)(ws + 8388608);
    __bf16* wkb = (__bf16*)(ws + 10485760);
    __bf16* wvb = (__bf16*)(ws + 12582912);
    __bf16* wob = (__bf16*)(ws + 14680064);
    __bf16* Qb  = (__bf16*)(ws + 16777216);
    __bf16* Kb  = (__bf16*)(ws + 25165824);
    __bf16* Vb  = (__bf16*)(ws + 33554432);
    __bf16* Ab  = (__bf16*)(ws + 41943040);

    const int M = BATCH * S_LEN;  // 4096
    const int N = EMB;            // 1024
    const int K = EMB;            // 1024

    f2b_kernel<<<(M * K / 4 + 255) / 256, 256, 0, stream>>>(x, xb, M * K / 4);
    f2b4_kernel<<<dim3(N * K / 4 / 256, 4), 256, 0, stream>>>(
        Wq, Wk, Wv, Wo, wqb, wkb, wvb, wob, N * K / 4);

    gemm_qkv<<<dim3(24, M / 128), 256, 0, stream>>>(
        xb, wqb, wkb, wvb, bq, bk, bv, Qb, Kb, Vb, M, N, K);

    // grid: x = bh (32), y = qt (16)  -> XCD-uniform work distribution
    attn2_kernel<<<dim3(BATCH * NHEAD, S_LEN / 128), 256, 0, stream>>>(Qb, Kb, Vb, Ab);

    gemm_nt<0><<<dim3(N / 128, M / 128), 256, 0, stream>>>(Ab, wob, bo, out, M, N, K);
}

// Round 4
// 146.998 us; speedup vs baseline: 2.2376x; 1.0618x over previous
//
#include <hip/hip_runtime.h>
#include <hip/hip_bf16.h>
#include <stdint.h>

#define BATCH 2
#define S_LEN 2048
#define EMB   1024
#define NHEAD 16
#define HDIM  64

typedef __attribute__((ext_vector_type(8)))  __bf16 bf16x8;
typedef __attribute__((ext_vector_type(4)))  __bf16 bf16x4;
typedef __attribute__((ext_vector_type(4)))  float  f32x4;
typedef __attribute__((ext_vector_type(16))) float  f32x16;

#define ZERO16 ((f32x16){0.f,0.f,0.f,0.f,0.f,0.f,0.f,0.f,0.f,0.f,0.f,0.f,0.f,0.f,0.f,0.f})
#define SM_SCALE_LOG2 0.18033688011112042f  /* 0.125 * log2(e) */

static __device__ __forceinline__ void gload_lds16(const void* g, void* l) {
    __builtin_amdgcn_global_load_lds(
        (__attribute__((address_space(1))) void*)g,
        (__attribute__((address_space(3))) void*)l,
        16, 0, 0);
}

// ---------------------------------------------------------------------------
// fp32 -> bf16 conversions
// ---------------------------------------------------------------------------
__global__ void f2b_kernel(const float* __restrict__ s, __bf16* __restrict__ d, int n4) {
    int i = blockIdx.x * blockDim.x + threadIdx.x;
    if (i >= n4) return;
    float4 v = reinterpret_cast<const float4*>(s)[i];
    bf16x4 o = { (__bf16)v.x, (__bf16)v.y, (__bf16)v.z, (__bf16)v.w };
    reinterpret_cast<bf16x4*>(d)[i] = o;
}

__global__ void f2b4_kernel(const float* __restrict__ s0, const float* __restrict__ s1,
                            const float* __restrict__ s2, const float* __restrict__ s3,
                            __bf16* __restrict__ d0, __bf16* __restrict__ d1,
                            __bf16* __restrict__ d2, __bf16* __restrict__ d3, int n4) {
    int i = blockIdx.x * blockDim.x + threadIdx.x;
    if (i >= n4) return;
    const float* s = blockIdx.y == 0 ? s0 : blockIdx.y == 1 ? s1 : blockIdx.y == 2 ? s2 : s3;
    __bf16*      d = blockIdx.y == 0 ? d0 : blockIdx.y == 1 ? d1 : blockIdx.y == 2 ? d2 : d3;
    float4 v = reinterpret_cast<const float4*>(s)[i];
    bf16x4 o = { (__bf16)v.x, (__bf16)v.y, (__bf16)v.z, (__bf16)v.w };
    reinterpret_cast<bf16x4*>(d)[i] = o;
}

// ---------------------------------------------------------------------------
// NT GEMM core (128x128 tile, 4 waves, 4x4 of 16x16x32), used for final proj
// ---------------------------------------------------------------------------
template <int OUT_MODE>
__global__ __launch_bounds__(256)
void gemm_nt(const __bf16* __restrict__ A, const __bf16* __restrict__ W,
             const float* __restrict__ bias, void* __restrict__ out,
             int M, int N, int K) {
    __shared__ __align__(16) __bf16 As[128 * 32];
    __shared__ __align__(16) __bf16 Bs[128 * 32];

    const int t    = threadIdx.x;
    const int w    = t >> 6;
    const int lane = t & 63;
    const int m0   = blockIdx.y * 128;
    const int n0   = blockIdx.x * 128;
    const int wr   = (w >> 1) * 64;
    const int wc   = (w & 1) * 64;
    const int fr   = lane & 15;
    const int kg   = (lane >> 4) * 8;

    f32x4 acc[4][4];
#pragma unroll
    for (int i = 0; i < 4; ++i)
#pragma unroll
        for (int j = 0; j < 4; ++j) acc[i][j] = (f32x4){0.f, 0.f, 0.f, 0.f};

    for (int kt = 0; kt < K; kt += 32) {
#pragma unroll
        for (int i = 0; i < 2; ++i) {
            int chunk = i * 256 + t;
            int row   = chunk >> 2;
            int col   = (chunk & 3) * 8;
            gload_lds16(A + (size_t)(m0 + row) * K + kt + col,
                        (char*)As + i * 4096 + w * 1024);
            gload_lds16(W + (size_t)(n0 + row) * K + kt + col,
                        (char*)Bs + i * 4096 + w * 1024);
        }
        __syncthreads();

        bf16x8 af[4], bfv[4];
#pragma unroll
        for (int m = 0; m < 4; ++m)
            af[m] = *(const bf16x8*)&As[(wr + m * 16 + fr) * 32 + kg];
#pragma unroll
        for (int n = 0; n < 4; ++n)
            bfv[n] = *(const bf16x8*)&Bs[(wc + n * 16 + fr) * 32 + kg];
#pragma unroll
        for (int m = 0; m < 4; ++m)
#pragma unroll
            for (int n = 0; n < 4; ++n)
                acc[m][n] = __builtin_amdgcn_mfma_f32_16x16x32_bf16(
                    af[m], bfv[n], acc[m][n], 0, 0, 0);
        __syncthreads();
    }

    const int rbase = (lane >> 4) * 4;
#pragma unroll
    for (int m = 0; m < 4; ++m) {
#pragma unroll
        for (int n = 0; n < 4; ++n) {
            int col  = n0 + wc + n * 16 + fr;
            float bv = bias[col];
#pragma unroll
            for (int j = 0; j < 4; ++j) {
                int row = m0 + wr + m * 16 + rbase + j;
                float v = acc[m][n][j] + bv;
                if (OUT_MODE == 0) {
                    ((float*)out)[(size_t)row * N + col] = v;
                } else {
                    int b = row >> 11, s = row & (S_LEN - 1);
                    int h = col >> 6,  d = col & (HDIM - 1);
                    ((__bf16*)out)[(((size_t)(b * NHEAD + h)) * S_LEN + s) * HDIM + d] =
                        (__bf16)v;
                }
            }
        }
    }
}

// ---------------------------------------------------------------------------
// Fused QKV projection: 3 NT GEMMs in one grid; which = blockIdx.x>>3
// ---------------------------------------------------------------------------
__global__ __launch_bounds__(256)
void gemm_qkv(const __bf16* __restrict__ A,
              const __bf16* __restrict__ W0p, const __bf16* __restrict__ W1p,
              const __bf16* __restrict__ W2p,
              const float* __restrict__ b0p, const float* __restrict__ b1p,
              const float* __restrict__ b2p,
              __bf16* __restrict__ o0, __bf16* __restrict__ o1,
              __bf16* __restrict__ o2, int M, int N, int K) {
    __shared__ __align__(16) __bf16 As[128 * 32];
    __shared__ __align__(16) __bf16 Bs[128 * 32];

    const int which = blockIdx.x >> 3;
    const __bf16* W    = which == 0 ? W0p : which == 1 ? W1p : W2p;
    const float*  bias = which == 0 ? b0p : which == 1 ? b1p : b2p;
    __bf16*       out  = which == 0 ? o0  : which == 1 ? o1  : o2;

    const int t    = threadIdx.x;
    const int w    = t >> 6;
    const int lane = t & 63;
    const int m0   = blockIdx.y * 128;
    const int n0   = (blockIdx.x & 7) * 128;
    const int wr   = (w >> 1) * 64;
    const int wc   = (w & 1) * 64;
    const int fr   = lane & 15;
    const int kg   = (lane >> 4) * 8;

    f32x4 acc[4][4];
#pragma unroll
    for (int i = 0; i < 4; ++i)
#pragma unroll
        for (int j = 0; j < 4; ++j) acc[i][j] = (f32x4){0.f, 0.f, 0.f, 0.f};

    for (int kt = 0; kt < K; kt += 32) {
#pragma unroll
        for (int i = 0; i < 2; ++i) {
            int chunk = i * 256 + t;
            int row   = chunk >> 2;
            int col   = (chunk & 3) * 8;
            gload_lds16(A + (size_t)(m0 + row) * K + kt + col,
                        (char*)As + i * 4096 + w * 1024);
            gload_lds16(W + (size_t)(n0 + row) * K + kt + col,
                        (char*)Bs + i * 4096 + w * 1024);
        }
        __syncthreads();

        bf16x8 af[4], bfv[4];
#pragma unroll
        for (int m = 0; m < 4; ++m)
            af[m] = *(const bf16x8*)&As[(wr + m * 16 + fr) * 32 + kg];
#pragma unroll
        for (int n = 0; n < 4; ++n)
            bfv[n] = *(const bf16x8*)&Bs[(wc + n * 16 + fr) * 32 + kg];
#pragma unroll
        for (int m = 0; m < 4; ++m)
#pragma unroll
            for (int n = 0; n < 4; ++n)
                acc[m][n] = __builtin_amdgcn_mfma_f32_16x16x32_bf16(
                    af[m], bfv[n], acc[m][n], 0, 0, 0);
        __syncthreads();
    }

    const int rbase = (lane >> 4) * 4;
#pragma unroll
    for (int m = 0; m < 4; ++m) {
#pragma unroll
        for (int n = 0; n < 4; ++n) {
            int col  = n0 + wc + n * 16 + fr;
            float bv = bias[col];
#pragma unroll
            for (int j = 0; j < 4; ++j) {
                int row = m0 + wr + m * 16 + rbase + j;
                float v = acc[m][n][j] + bv;
                int b = row >> 11, s = row & (S_LEN - 1);
                int h = col >> 6,  d = col & (HDIM - 1);
                out[(((size_t)(b * NHEAD + h)) * S_LEN + s) * HDIM + d] = (__bf16)v;
            }
        }
    }
}

// ---------------------------------------------------------------------------
// Block-causal flash attention, split-KV 8-wave structure.
// Grid (x=bh 32, y=qt 16), block 512 thr = 8 waves. q-tile 128 = 4 q-blocks;
// wave w: q-block 4qt+(w&3), kv-half h2=w>>2. 128 keys staged per iter
// (K: gload_lds XOR-swizzled; V: reg-transposed [d][key^..]), double-buffered.
// Wave computes its 64-key half (2 causal 32-sub-blocks). Online softmax
// per-lane (swapped QK^T), pair (w, w+4) merged via LDS at the end.
// ---------------------------------------------------------------------------
__global__ __launch_bounds__(512, 4)
void attn3_kernel(const __bf16* __restrict__ Q, const __bf16* __restrict__ Kv,
                  const __bf16* __restrict__ V, __bf16* __restrict__ out) {
    __shared__ __align__(16) __bf16 Kt[2][128 * 64];   // [key][dgran ^ (key&7)]
    __shared__ __align__(16) __bf16 Vt[2][64 * 128];   // [d][key ^ ((d&7)<<3)]
    __shared__ float bc[8][32];

    const int t    = threadIdx.x;
    const int w8   = t >> 6;
    const int lane = t & 63;
    const int h    = lane >> 5;
    const int q32  = lane & 31;
    const int j    = w8 & 3;
    const int h2   = w8 >> 2;
    const int bh   = blockIdx.x;   // 0..31
    const int qt   = blockIdx.y;   // 0..15
    const int qb   = 4 * qt + j;   // this wave's q-block (32 rows)

    const __bf16* Qp = Q  + (size_t)bh * S_LEN * HDIM;
    const __bf16* Kp = Kv + (size_t)bh * S_LEN * HDIM;
    const __bf16* Vp = V  + (size_t)bh * S_LEN * HDIM;

    const int qrow = qb * 32 + q32;

    // Q fragments (B-operand of S^T mfma): col=q32, k=d=16ks+8h+e
    bf16x8 qreg[4];
#pragma unroll
    for (int ks = 0; ks < 4; ++ks)
        qreg[ks] = *(const bf16x8*)&Qp[(size_t)qrow * HDIM + 16 * ks + 8 * h];

    f32x16 oacc0 = ZERO16, oacc1 = ZERO16;    // O cols d=q32 / 32+q32
    float mrun = -1e30f, lrun = 0.f;

    // ---- prologue: stage chunk 0 (keys 0..127) ----
    {
#pragma unroll
        for (int i = 0; i < 2; ++i) {
            int c16 = i * 512 + t;            // 0..1023
            int key = c16 >> 3;               // 0..127
            int d0  = ((c16 & 7) ^ (key & 7)) * 8;
            gload_lds16(Kp + (size_t)key * HDIM + d0, (char*)&Kt[0][0] + c16 * 16);
        }
        bf16x8 vr[2];
#pragma unroll
        for (int i = 0; i < 2; ++i)
            vr[i] = *(const bf16x8*)&Vp[(size_t)(64 * h2 + lane) * HDIM + (4 * i + j) * 8];
#pragma unroll
        for (int i = 0; i < 2; ++i) {
            int d0 = (4 * i + j) * 8;
            int key = 64 * h2 + lane;
#pragma unroll
            for (int e = 0; e < 8; ++e) {
                int d = d0 + e;
                Vt[0][d * 128 + (key ^ ((d & 7) << 3))] = vr[i][e];
            }
        }
        __syncthreads();
    }

    for (int c = 0; c <= qt; ++c) {
        const int  cur = c & 1;
        const bool pre = (c < qt);
        bf16x8 vr[2];
        if (pre) {
            const int kb = (c + 1) * 128;
#pragma unroll
            for (int i = 0; i < 2; ++i) {
                int c16 = i * 512 + t;
                int key = c16 >> 3;
                int d0  = ((c16 & 7) ^ (key & 7)) * 8;
                gload_lds16(Kp + (size_t)(kb + key) * HDIM + d0,
                            (char*)&Kt[cur ^ 1][0] + c16 * 16);
            }
#pragma unroll
            for (int i = 0; i < 2; ++i)
                vr[i] = *(const bf16x8*)&Vp[(size_t)(kb + 64 * h2 + lane) * HDIM +
                                            (4 * i + j) * 8];
        }

        // causal sub-block count for this wave in this 128-chunk
        int ns;
        if (pre) ns = 2;
        else     ns = h2 ? (j == 3 ? 2 : (j == 2 ? 1 : 0)) : (j == 0 ? 1 : 2);

        for (int u = 0; u < ns; ++u) {
            const int klocal = 64 * h2 + 32 * u;   // local key base in staged chunk

            // S^T = K . Q^T  (rows=key, cols=q)
            f32x16 sac = ZERO16;
#pragma unroll
            for (int ks = 0; ks < 4; ++ks) {
                bf16x8 kf = *(const bf16x8*)&Kt[cur][(klocal + q32) * 64 +
                                ((16 * ks + 8 * h) ^ ((q32 & 7) << 3))];
                sac = __builtin_amdgcn_mfma_f32_32x32x16_bf16(kf, qreg[ks], sac, 0, 0, 0);
            }

            // per-lane softmax (log2 domain), in place in sac
#pragma unroll
            for (int r = 0; r < 16; ++r) sac[r] = sac[r] * SM_SCALE_LOG2;
            float pmax = sac[0];
#pragma unroll
            for (int r = 1; r < 16; ++r) pmax = fmaxf(pmax, sac[r]);
            pmax = fmaxf(pmax, __shfl_xor(pmax, 32));

            if (__any(pmax > mrun + 8.f)) {
                float mnew = fmaxf(mrun, pmax);
                float fac  = exp2f(mrun - mnew);
                mrun = mnew;
                lrun *= fac;
                bc[w8][q32] = fac;
                asm volatile("s_waitcnt lgkmcnt(0)" ::: "memory");
                __builtin_amdgcn_sched_barrier(0);
#pragma unroll
                for (int q2 = 0; q2 < 4; ++q2) {
                    f32x4 fv = *(const f32x4*)&bc[w8][8 * q2 + 4 * h];
#pragma unroll
                    for (int jj = 0; jj < 4; ++jj) {
                        oacc0[4 * q2 + jj] *= fv[jj];
                        oacc1[4 * q2 + jj] *= fv[jj];
                    }
                }
            }

            float ps = 0.f;
#pragma unroll
            for (int r = 0; r < 16; ++r) {
                float pv = exp2f(sac[r] - mrun);
                ps += pv;
                sac[r] = pv;
            }
            ps += __shfl_xor(ps, 32);
            lrun += ps;

            // pack P rows to bf16 words
            unsigned L[4], H[4];
#pragma unroll
            for (int g = 0; g < 4; ++g) {
                __bf16 b0 = (__bf16)sac[4 * g],     b1 = (__bf16)sac[4 * g + 1];
                __bf16 b2 = (__bf16)sac[4 * g + 2], b3 = (__bf16)sac[4 * g + 3];
                L[g] = (unsigned)*(unsigned short*)&b0 |
                       ((unsigned)*(unsigned short*)&b1 << 16);
                H[g] = (unsigned)*(unsigned short*)&b2 |
                       ((unsigned)*(unsigned short*)&b3 << 16);
            }

#pragma unroll
            for (int s2 = 0; s2 < 2; ++s2) {
                unsigned a0 = L[2 * s2], b0 = L[2 * s2 + 1];
                unsigned a1 = H[2 * s2], b1 = H[2 * s2 + 1];
                asm("v_permlane32_swap_b32 %0, %1" : "+v"(a0), "+v"(b0));
                asm("v_permlane32_swap_b32 %0, %1" : "+v"(a1), "+v"(b1));
                unsigned wvw[4] = { a0, a1, b0, b1 };
                bf16x8 pa = *(bf16x8*)wvw;

                const int klb = klocal + 16 * s2;
#pragma unroll
                for (int n = 0; n < 2; ++n) {
                    int d = 32 * n + q32;
                    bf16x8 vf = *(const bf16x8*)&Vt[cur][d * 128 +
                                    ((klb + 8 * h) ^ ((d & 7) << 3))];
                    if (n == 0)
                        oacc0 = __builtin_amdgcn_mfma_f32_32x32x16_bf16(pa, vf, oacc0, 0, 0, 0);
                    else
                        oacc1 = __builtin_amdgcn_mfma_f32_32x32x16_bf16(pa, vf, oacc1, 0, 0, 0);
                }
            }
        }

        if (pre) {
            const int buf = cur ^ 1;
            const int key = 64 * h2 + lane;
#pragma unroll
            for (int i = 0; i < 2; ++i) {
                int d0 = (4 * i + j) * 8;
#pragma unroll
                for (int e = 0; e < 8; ++e) {
                    int d = d0 + e;
                    Vt[buf][d * 128 + (key ^ ((d & 7) << 3))] = vr[i][e];
                }
            }
        }
        __syncthreads();
    }

    // ---- pair merge: waves (j, h2=0) <- (j, h2=1) ----
    // ML arrays alias Vt; Oex aliases Kt (all staged reads complete).
    float* MLm = (float*)&Vt[0][0];          // [8][32]
    float* MLl = MLm + 256;                  // [8][32]
    float* Oex = (float*)&Kt[0][0];          // [4][32][64]

    if (h == 0) { MLm[w8 * 32 + q32] = mrun; MLl[w8 * 32 + q32] = lrun; }
    if (h2 == 1) {
        float* ob = Oex + j * 2048;
#pragma unroll
        for (int q2 = 0; q2 < 4; ++q2)
#pragma unroll
            for (int jj = 0; jj < 4; ++jj) {
                int r  = 4 * q2 + jj;
                int rl = 8 * q2 + 4 * h + jj;
                ob[rl * 64 + q32]      = oacc0[r];
                ob[rl * 64 + 32 + q32] = oacc1[r];
            }
    }
    __syncthreads();

    if (h2 == 0) {
        const int b = bh >> 4, hh = bh & (NHEAD - 1);
        __bf16* op = out + (size_t)b * S_LEN * EMB + hh * HDIM;
        const float* ob = Oex + j * 2048;
#pragma unroll
        for (int q2 = 0; q2 < 4; ++q2) {
            f32x4 ma4 = *(const f32x4*)&MLm[j * 32 + 8 * q2 + 4 * h];
            f32x4 mb4 = *(const f32x4*)&MLm[(j + 4) * 32 + 8 * q2 + 4 * h];
            f32x4 la4 = *(const f32x4*)&MLl[j * 32 + 8 * q2 + 4 * h];
            f32x4 lb4 = *(const f32x4*)&MLl[(j + 4) * 32 + 8 * q2 + 4 * h];
#pragma unroll
            for (int jj = 0; jj < 4; ++jj) {
                float ma = ma4[jj], mb = mb4[jj];
                float mst = fmaxf(ma, mb);
                float sa  = exp2f(ma - mst), sb = exp2f(mb - mst);
                float inv = 1.f / (la4[jj] * sa + lb4[jj] * sb);
                int r  = 4 * q2 + jj;
                int rl = 8 * q2 + 4 * h + jj;
                int row = qb * 32 + rl;
                float v0 = (oacc0[r] * sa + ob[rl * 64 + q32] * sb) * inv;
                float v1 = (oacc1[r] * sa + ob[rl * 64 + 32 + q32] * sb) * inv;
                op[(size_t)row * EMB + q32]      = (__bf16)v0;
                op[(size_t)row * EMB + 32 + q32] = (__bf16)v1;
            }
        }
    }
}

// ---------------------------------------------------------------------------
extern "C" void kernel_launch(void* const* d_in, const int* in_sizes, int n_in,
                              void* d_out, int out_size, void* d_ws, size_t ws_size,
                              hipStream_t stream) {
    const float* x  = (const float*)d_in[0];
    const float* Wq = (const float*)d_in[1];
    const float* bq = (const float*)d_in[2];
    const float* Wk = (const float*)d_in[3];
    const float* bk = (const float*)d_in[4];
    const float* Wv = (const float*)d_in[5];
    const float* bv = (const float*)d_in[6];
    const float* Wo = (const float*)d_in[7];
    const float* bo = (const float*)d_in[8];
    float* out = (float*)d_out;

    char* ws = (char*)d_ws;
    __bf16* xb  = (__bf16*)(ws + 0);
    __bf16* wqb = (__bf16*)(ws + 8388608);
    __bf16* wkb = (__bf16*)(ws + 10485760);
    __bf16* wvb = (__bf16*)(ws + 12582912);
    __bf16* wob = (__bf16*)(ws + 14680064);
    __bf16* Qb  = (__bf16*)(ws + 16777216);
    __bf16* Kb  = (__bf16*)(ws + 25165824);
    __bf16* Vb  = (__bf16*)(ws + 33554432);
    __bf16* Ab  = (__bf16*)(ws + 41943040);

    const int M = BATCH * S_LEN;  // 4096
    const int N = EMB;            // 1024
    const int K = EMB;            // 1024

    f2b_kernel<<<(M * K / 4 + 255) / 256, 256, 0, stream>>>(x, xb, M * K / 4);
    f2b4_kernel<<<dim3(N * K / 4 / 256, 4), 256, 0, stream>>>(
        Wq, Wk, Wv, Wo, wqb, wkb, wvb, wob, N * K / 4);

    gemm_qkv<<<dim3(24, M / 128), 256, 0, stream>>>(
        xb, wqb, wkb, wvb, bq, bk, bv, Qb, Kb, Vb, M, N, K);

    // grid: x = bh (32), y = qt (16); 512-thread blocks, split-KV
    attn3_kernel<<<dim3(BATCH * NHEAD, S_LEN / 128), 512, 0, stream>>>(Qb, Kb, Vb, Ab);

    gemm_nt<0><<<dim3(N / 128, M / 128), 256, 0, stream>>>(Ab, wob, bo, out, M, N, K);
}